// Round 11
// baseline (77.051 us; speedup 1.0000x reference)
//
#include <hip/hip_runtime.h>

// Triplet margin loss: mean(relu(|a-p|^2 - |a-n|^2 + MARGIN)).
// batch: (N=4096, D=1024) fp32 (16 MB); triplets: (T=100000, 3) int32.
//
// Ladder: R1 137 -> R2 chunked fp32 55 (21-24 TB/s L2) -> R3 bf16 47.6 ->
// R4 fp8 36.5 -> R5 fp8+norm-identity 34.9 (BEST) -> R7 sort+NT 79.9 (NT
// kills L2 retention) -> R8/R10 2-trip unroll 41.6/39.9 (MLP falsified) ->
// R9 sdot4 39.1 (slow path). fp8 gather pinned at ~11-13 TB/s independent of
// VALU/chunking/MLP/occupancy -> suspect per-CU vL1 fill path (4MB random
// working set vs 32KB L1: ~1% hit, 100% fill churn).
// R11: R5 structure + (a) SC0 buffer loads for rows: bypass vL1, stay
// L2-cached (CPol bit0 on gfx940+; NOT bit1=NT, learned R7); (b) contiguous
// triplet range per wave (index loads walk one line); (c) last-block final
// reduce (one less launch; device-scope atomics + fences per G16).

constexpr float MARGIN = 0.2f;
constexpr int D = 1024;          // floats per row == bytes per fp8 row

typedef float f32x2 __attribute__((ext_vector_type(2)));
typedef int   i32x4 __attribute__((ext_vector_type(4)));

// CK-style raw buffer load intrinsic (battle-tested hipcc idiom).
__device__ i32x4 llvm_amdgcn_raw_buffer_load_i32x4(i32x4 srsrc, int voffset,
                                                   int soffset, int cpol)
    __asm("llvm.amdgcn.raw.buffer.load.v4i32");

__device__ __forceinline__ i32x4 make_rsrc(const void* p, int bytes)
{
    union { const void* p; uint u[2]; } cvt;
    cvt.p = p;
    i32x4 r;
    r.x = (int)cvt.u[0];
    r.y = (int)(cvt.u[1] & 0xffffu);   // base[47:32], stride=0
    r.z = bytes;                        // num_records (bytes, stride==0)
    r.w = 0x00020000;                   // raw untyped dword access
    return r;
}

// ---- Phase 0: fp32 -> fp8 e4m3 (HW RNE) + exact fp32 row norms ----
__global__ __launch_bounds__(256)
void convert_norm_kernel(const float* __restrict__ in,
                         uint* __restrict__ out8,
                         float* __restrict__ norms,
                         int* __restrict__ counter, int nrows)
{
    if (blockIdx.x == 0 && threadIdx.x == 0) *counter = 0;  // reset per call
    const int lane = threadIdx.x & 63;
    const int wib  = threadIdx.x >> 6;
    const int nw   = gridDim.x * 4;
    for (int row = blockIdx.x * 4 + wib; row < nrows; row += nw) {
        const float4* r4 = (const float4*)(in + (size_t)row * D);
        uint* o = out8 + (size_t)row * (D / 4);
        float nrm = 0.0f;
        #pragma unroll
        for (int k = 0; k < 4; ++k) {
            const float4 v = r4[lane + 64 * k];
            uint u = 0;
            u = (uint)__builtin_amdgcn_cvt_pk_fp8_f32(v.x, v.y, (int)u, false);
            u = (uint)__builtin_amdgcn_cvt_pk_fp8_f32(v.z, v.w, (int)u, true);
            o[lane + 64 * k] = u;
            nrm = fmaf(v.x, v.x, fmaf(v.y, v.y, fmaf(v.z, v.z, fmaf(v.w, v.w, nrm))));
        }
        #pragma unroll
        for (int off = 32; off > 0; off >>= 1) nrm += __shfl_xor(nrm, off, 64);
        if (lane == 0) norms[row] = nrm;
    }
}

// ---- dot = a.(n-p) over this lane's 16 fp8 elements ----
__device__ __forceinline__ float dot_apn(i32x4 av, i32x4 pv, i32x4 nv)
{
    float dot = 0.0f;
    #pragma unroll
    for (int j = 0; j < 4; ++j) {
        const int au = av[j], pu = pv[j], nu = nv[j];
        const f32x2 a0 = __builtin_amdgcn_cvt_pk_f32_fp8(au, false);
        const f32x2 a1 = __builtin_amdgcn_cvt_pk_f32_fp8(au, true);
        const f32x2 p0 = __builtin_amdgcn_cvt_pk_f32_fp8(pu, false);
        const f32x2 p1 = __builtin_amdgcn_cvt_pk_f32_fp8(pu, true);
        const f32x2 n0 = __builtin_amdgcn_cvt_pk_f32_fp8(nu, false);
        const f32x2 n1 = __builtin_amdgcn_cvt_pk_f32_fp8(nu, true);
        dot = fmaf(a0.x, n0.x - p0.x, dot);
        dot = fmaf(a0.y, n0.y - p0.y, dot);
        dot = fmaf(a1.x, n1.x - p1.x, dot);
        dot = fmaf(a1.y, n1.y - p1.y, dot);
    }
    return dot;
}

// ---- Phase 1: one wave per contiguous triplet range; SC0 row loads;
//      last block folds the final mean (device-scope atomics, G16) ----
__global__ __launch_bounds__(256)
void triplet_dot_kernel(const unsigned char* __restrict__ batch8,
                        const int*   __restrict__ trip,
                        const float* __restrict__ norms,
                        float*       __restrict__ partials,
                        int*         __restrict__ counter,
                        float*       __restrict__ out,
                        int T, int nd_bytes, int nblocks, float invT)
{
    const int lane = threadIdx.x & 63;
    const int wib  = threadIdx.x >> 6;
    const int wid  = blockIdx.x * 4 + wib;
    const int nw   = gridDim.x * 4;

    const i32x4 rsrc = make_rsrc(batch8, nd_bytes);
    const int laneoff = lane * 16;

    // contiguous range per wave: index loads stay within ~1 cache line
    const int TR = (T + nw - 1) / nw;
    const int t0 = wid * TR;
    const int t1 = (t0 + TR < T) ? (t0 + TR) : T;

    float acc = 0.0f;
    for (int t = t0; t < t1; ++t) {
        const int ia  = trip[3 * t + 0];
        const int ip  = trip[3 * t + 1];
        const int in_ = trip[3 * t + 2];

        // SC0 (cpol=1): bypass vL1, cache in L2. NOT NT (R7 lesson).
        const i32x4 av = llvm_amdgcn_raw_buffer_load_i32x4(rsrc, ia * (int)D + laneoff, 0, 1);
        const i32x4 pv = llvm_amdgcn_raw_buffer_load_i32x4(rsrc, ip * (int)D + laneoff, 0, 1);
        const i32x4 nv = llvm_amdgcn_raw_buffer_load_i32x4(rsrc, in_ * (int)D + laneoff, 0, 1);

        float d = dot_apn(av, pv, nv);
        #pragma unroll
        for (int off = 32; off > 0; off >>= 1) d += __shfl_xor(d, off, 64);

        const float loss = norms[ip] - norms[in_] + 2.0f * d + MARGIN;
        acc += loss > 0.0f ? loss : 0.0f;
    }

    __shared__ float s[4];
    __shared__ int islast;
    if (lane == 0) s[wib] = acc;
    __syncthreads();
    if (threadIdx.x == 0) {
        const float blocksum = (s[0] + s[1]) + (s[2] + s[3]);
        atomicExch(&partials[blockIdx.x], blocksum);   // coherent-point write
        __threadfence();                               // release
        const int old = atomicAdd(counter, 1);         // device-scope
        islast = (old == nblocks - 1);
    }
    __syncthreads();
    if (islast) {
        __threadfence();                               // acquire
        __shared__ float r[256];
        float a = 0.0f;
        for (int i = threadIdx.x; i < nblocks; i += 256)
            a += atomicAdd(&partials[i], 0.0f);        // coherent-point read
        r[threadIdx.x] = a;
        __syncthreads();
        #pragma unroll
        for (int st = 128; st > 0; st >>= 1) {
            if (threadIdx.x < st) r[threadIdx.x] += r[threadIdx.x + st];
            __syncthreads();
        }
        if (threadIdx.x == 0) out[0] = r[0] * invT;    // fixed-order sum: deterministic
    }
}

// ---- standalone final reduce (fallback path only) ----
__global__ __launch_bounds__(256)
void final_mean_kernel(const float* __restrict__ part, int n,
                       float* __restrict__ out, float invT)
{
    __shared__ float s[256];
    float acc = 0.0f;
    for (int i = threadIdx.x; i < n; i += 256) acc += part[i];
    s[threadIdx.x] = acc;
    __syncthreads();
    #pragma unroll
    for (int st = 128; st > 0; st >>= 1) {
        if (threadIdx.x < st) s[threadIdx.x] += s[threadIdx.x + st];
        __syncthreads();
    }
    if (threadIdx.x == 0) out[0] = s[0] * invT;
}

// ---- Fallback (fp32, one wave per triplet): correctness-safe path ----
__global__ __launch_bounds__(256)
void triplet_full_kernel(const float* __restrict__ batch,
                         const int*   __restrict__ trip,
                         float*       __restrict__ partials, int T)
{
    const int lane = threadIdx.x & 63;
    const int wib  = threadIdx.x >> 6;
    const int wave_id = blockIdx.x * 4 + wib;
    const int n_waves = gridDim.x * 4;

    float acc = 0.0f;
    for (int t = wave_id; t < T; t += n_waves) {
        const int ia  = trip[3 * t + 0];
        const int ip  = trip[3 * t + 1];
        const int in_ = trip[3 * t + 2];
        const float4* A  = (const float4*)(batch + (size_t)ia * D);
        const float4* P  = (const float4*)(batch + (size_t)ip * D);
        const float4* Nv = (const float4*)(batch + (size_t)in_ * D);
        float dap = 0.0f, dan = 0.0f;
        #pragma unroll
        for (int c = 0; c < 4; ++c) {
            const int idx = lane + c * 64;
            float4 av = A[idx], pv = P[idx], nv = Nv[idx];
            float d;
            d = av.x - pv.x; dap += d * d;
            d = av.y - pv.y; dap += d * d;
            d = av.z - pv.z; dap += d * d;
            d = av.w - pv.w; dap += d * d;
            d = av.x - nv.x; dan += d * d;
            d = av.y - nv.y; dan += d * d;
            d = av.z - nv.z; dan += d * d;
            d = av.w - nv.w; dan += d * d;
        }
        float diff = dap - dan;
        #pragma unroll
        for (int off = 32; off > 0; off >>= 1) diff += __shfl_xor(diff, off, 64);
        const float loss = diff + MARGIN;
        acc += loss > 0.0f ? loss : 0.0f;
    }
    __shared__ float s[4];
    if (lane == 0) s[wib] = acc;
    __syncthreads();
    if (threadIdx.x == 0) partials[blockIdx.x] = (s[0] + s[1]) + (s[2] + s[3]);
}

static inline size_t align256(size_t x) { return (x + 255) & ~(size_t)255; }

extern "C" void kernel_launch(void* const* d_in, const int* in_sizes, int n_in,
                              void* d_out, int out_size, void* d_ws, size_t ws_size,
                              hipStream_t stream)
{
    const float* batch = (const float*)d_in[0];
    const int*   trip  = (const int*)d_in[1];
    float* out = (float*)d_out;
    const int T     = in_sizes[1] / 3;
    const int ND    = in_sizes[0];
    const int nrows = ND / D;

    const int BLOCKS = 2048;
    const size_t fp8_bytes  = align256((size_t)ND);
    const size_t norm_bytes = align256((size_t)nrows * sizeof(float));
    const size_t part_bytes = align256((size_t)BLOCKS * sizeof(float));
    const size_t need = fp8_bytes + norm_bytes + part_bytes + 256;

    if (ws_size >= need) {
        unsigned char* batch8 = (unsigned char*)d_ws;
        float* norms    = (float*)((char*)d_ws + fp8_bytes);
        float* partials = (float*)((char*)d_ws + fp8_bytes + norm_bytes);
        int*   counter  = (int*)((char*)d_ws + fp8_bytes + norm_bytes + part_bytes);
        convert_norm_kernel<<<1024, 256, 0, stream>>>(batch, (uint*)batch8, norms,
                                                      counter, nrows);
        triplet_dot_kernel<<<BLOCKS, 256, 0, stream>>>(batch8, trip, norms, partials,
                                                       counter, out, T, ND, BLOCKS,
                                                       1.0f / (float)T);
    } else {
        float* partials = (float*)d_ws;  // 8 KB
        triplet_full_kernel<<<BLOCKS, 256, 0, stream>>>(batch, trip, partials, T);
        final_mean_kernel<<<1, 256, 0, stream>>>(partials, BLOCKS, out, 1.0f / (float)T);
    }
}

// Round 12
// 44.641 us; speedup vs baseline: 1.7260x; 1.7260x over previous
//
#include <hip/hip_runtime.h>

// Triplet margin loss: mean(relu(|a-p|^2 - |a-n|^2 + MARGIN)).
// batch: (N=4096, D=1024) fp32 (16 MB); triplets: (T=100000, 3) int32.
//
// Ladder: R1 137 -> R2 chunked fp32 55 -> R3 bf16 47.6 -> R4 fp8 36.5 ->
// R5 fp8+norm-identity 34.9 (prev BEST) -> R7 NT 79.9 / R8 41.6 / R9 39.1 /
// R10 39.9 / R11 SC0 77.0 (all falsified levers). Random gather through the
// per-CU L1 path is pinned at ~11-13 TB/s regardless of bytes/VALU/MLP/
// occupancy/cache-policy.
// R12: kill the random GLOBAL gather. fp8 batch column-chunk of 32 B x 4096
// rows = 128 KB -> LDS, stored TRANSPOSED (plane[j][row], bank=row%32 ->
// random-row b32 reads are ~2-way = conflict-free, m136). One block per CU
// owns one chunk; threads compute per-triplet 32-elem dots from LDS only.
// Norms identity + relu fold into phase 2 over [32][T] chunk partials.

constexpr float MARGIN = 0.2f;
constexpr int D = 1024;          // floats per row == bytes per fp8 row
constexpr int NROW = 4096;       // max rows supported by LDS plan
constexpr int NCH = 32;          // chunks of 32 B
constexpr int CBLK = 8;          // blocks per chunk
constexpr int NBLK = NCH * CBLK; // 256 blocks = 1 per CU

typedef float f32x2 __attribute__((ext_vector_type(2)));
typedef uint  u32x4 __attribute__((ext_vector_type(4)));

// ---- Phase 0: fp32 -> fp8 e4m3 (HW RNE) + exact fp32 row norms ----
__global__ __launch_bounds__(256)
void convert_norm_kernel(const float* __restrict__ in,
                         uint* __restrict__ out8,
                         float* __restrict__ norms, int nrows)
{
    const int lane = threadIdx.x & 63;
    const int wib  = threadIdx.x >> 6;
    const int nw   = gridDim.x * 4;
    for (int row = blockIdx.x * 4 + wib; row < nrows; row += nw) {
        const float4* r4 = (const float4*)(in + (size_t)row * D);
        uint* o = out8 + (size_t)row * (D / 4);
        float nrm = 0.0f;
        #pragma unroll
        for (int k = 0; k < 4; ++k) {
            const float4 v = r4[lane + 64 * k];
            uint u = 0;
            u = (uint)__builtin_amdgcn_cvt_pk_fp8_f32(v.x, v.y, (int)u, false);
            u = (uint)__builtin_amdgcn_cvt_pk_fp8_f32(v.z, v.w, (int)u, true);
            o[lane + 64 * k] = u;
            nrm = fmaf(v.x, v.x, fmaf(v.y, v.y, fmaf(v.z, v.z, fmaf(v.w, v.w, nrm))));
        }
        #pragma unroll
        for (int off = 32; off > 0; off >>= 1) nrm += __shfl_xor(nrm, off, 64);
        if (lane == 0) norms[row] = nrm;
    }
}

// ---- Phase 1: stage chunk into LDS (transposed), dot from LDS only ----
__global__ __launch_bounds__(512)
void stage_dot_kernel(const uint* __restrict__ batch8,   // [nrows][256] dwords
                      const int*  __restrict__ trip,
                      float*      __restrict__ chunk_part, // [NCH][T]
                      int T, int nrows)
{
    // plane j (j=0..7) holds dword j of every row's chunk: bank = row % 32.
    __shared__ uint lds[8 * NROW];                 // 128 KB

    const int c     = blockIdx.x & (NCH - 1);      // chunk id
    const int bslot = blockIdx.x >> 5;             // 0..CBLK-1
    const int tid   = threadIdx.x;

    // ---- stage: 4096 rows x 32 B, consecutive threads read consecutive rows
    #pragma unroll
    for (int k = 0; k < NROW / 512; ++k) {
        const int r = k * 512 + tid;
        if (r < nrows) {
            const uint* src = batch8 + (size_t)r * 256 + c * 8;
            const u32x4 w0 = *(const u32x4*)(src);
            const u32x4 w1 = *(const u32x4*)(src + 4);
            #pragma unroll
            for (int j = 0; j < 4; ++j) {
                lds[j * NROW + r]       = w0[j];
                lds[(j + 4) * NROW + r] = w1[j];
            }
        }
    }
    __syncthreads();

    // ---- dot: each thread owns triplets; all row data comes from LDS
    const int TR = (T + CBLK - 1) / CBLK;
    const int t0 = bslot * TR;
    const int t1 = (t0 + TR < T) ? (t0 + TR) : T;

    for (int t = t0 + tid; t < t1; t += 512) {
        const int ia  = trip[3 * t + 0];
        const int ip  = trip[3 * t + 1];
        const int in_ = trip[3 * t + 2];

        float dot = 0.0f;
        #pragma unroll
        for (int j = 0; j < 8; ++j) {
            const uint au = lds[j * NROW + ia];
            const uint pu = lds[j * NROW + ip];
            const uint nu = lds[j * NROW + in_];
            const f32x2 a0 = __builtin_amdgcn_cvt_pk_f32_fp8((int)au, false);
            const f32x2 a1 = __builtin_amdgcn_cvt_pk_f32_fp8((int)au, true);
            const f32x2 p0 = __builtin_amdgcn_cvt_pk_f32_fp8((int)pu, false);
            const f32x2 p1 = __builtin_amdgcn_cvt_pk_f32_fp8((int)pu, true);
            const f32x2 n0 = __builtin_amdgcn_cvt_pk_f32_fp8((int)nu, false);
            const f32x2 n1 = __builtin_amdgcn_cvt_pk_f32_fp8((int)nu, true);
            dot = fmaf(a0.x, n0.x - p0.x, dot);
            dot = fmaf(a0.y, n0.y - p0.y, dot);
            dot = fmaf(a1.x, n1.x - p1.x, dot);
            dot = fmaf(a1.y, n1.y - p1.y, dot);
        }
        chunk_part[(size_t)c * T + t] = dot;       // coalesced store
    }
}

// ---- Phase 2: sum 32 chunk dots + norm identity + relu -> block partials ----
__global__ __launch_bounds__(256)
void chunk_reduce_kernel(const float* __restrict__ chunk_part,
                         const int*   __restrict__ trip,
                         const float* __restrict__ norms,
                         float*       __restrict__ part2, int T)
{
    float acc = 0.0f;
    for (int t = blockIdx.x * 256 + threadIdx.x; t < T; t += gridDim.x * 256) {
        float s = 0.0f;
        #pragma unroll
        for (int c = 0; c < NCH; ++c) s += chunk_part[(size_t)c * T + t];
        const int ip  = trip[3 * t + 1];
        const int in_ = trip[3 * t + 2];
        const float loss = norms[ip] - norms[in_] + 2.0f * s + MARGIN;
        acc += loss > 0.0f ? loss : 0.0f;
    }
    __shared__ float s[256];
    s[threadIdx.x] = acc;
    __syncthreads();
    #pragma unroll
    for (int st = 128; st > 0; st >>= 1) {
        if (threadIdx.x < st) s[threadIdx.x] += s[threadIdx.x + st];
        __syncthreads();
    }
    if (threadIdx.x == 0) part2[blockIdx.x] = s[0];
}

// ---- final scalar ----
__global__ __launch_bounds__(256)
void final_mean_kernel(const float* __restrict__ part, int n,
                       float* __restrict__ out, float invT)
{
    __shared__ float s[256];
    float acc = 0.0f;
    for (int i = threadIdx.x; i < n; i += 256) acc += part[i];
    s[threadIdx.x] = acc;
    __syncthreads();
    #pragma unroll
    for (int st = 128; st > 0; st >>= 1) {
        if (threadIdx.x < st) s[threadIdx.x] += s[threadIdx.x + st];
        __syncthreads();
    }
    if (threadIdx.x == 0) out[0] = s[0] * invT;
}

// ---- Fallback (fp32, one wave per triplet): correctness-safe path ----
__global__ __launch_bounds__(256)
void triplet_full_kernel(const float* __restrict__ batch,
                         const int*   __restrict__ trip,
                         float*       __restrict__ partials, int T)
{
    const int lane = threadIdx.x & 63;
    const int wib  = threadIdx.x >> 6;
    const int wave_id = blockIdx.x * 4 + wib;
    const int n_waves = gridDim.x * 4;

    float acc = 0.0f;
    for (int t = wave_id; t < T; t += n_waves) {
        const int ia  = trip[3 * t + 0];
        const int ip  = trip[3 * t + 1];
        const int in_ = trip[3 * t + 2];
        const float4* A  = (const float4*)(batch + (size_t)ia * D);
        const float4* P  = (const float4*)(batch + (size_t)ip * D);
        const float4* Nv = (const float4*)(batch + (size_t)in_ * D);
        float dap = 0.0f, dan = 0.0f;
        #pragma unroll
        for (int cc = 0; cc < 4; ++cc) {
            const int idx = lane + cc * 64;
            float4 av = A[idx], pv = P[idx], nv = Nv[idx];
            float d;
            d = av.x - pv.x; dap += d * d;
            d = av.y - pv.y; dap += d * d;
            d = av.z - pv.z; dap += d * d;
            d = av.w - pv.w; dap += d * d;
            d = av.x - nv.x; dan += d * d;
            d = av.y - nv.y; dan += d * d;
            d = av.z - nv.z; dan += d * d;
            d = av.w - nv.w; dan += d * d;
        }
        float diff = dap - dan;
        #pragma unroll
        for (int off = 32; off > 0; off >>= 1) diff += __shfl_xor(diff, off, 64);
        const float loss = diff + MARGIN;
        acc += loss > 0.0f ? loss : 0.0f;
    }
    __shared__ float s[4];
    if (lane == 0) s[wib] = acc;
    __syncthreads();
    if (threadIdx.x == 0) partials[blockIdx.x] = (s[0] + s[1]) + (s[2] + s[3]);
}

static inline size_t align256(size_t x) { return (x + 255) & ~(size_t)255; }

extern "C" void kernel_launch(void* const* d_in, const int* in_sizes, int n_in,
                              void* d_out, int out_size, void* d_ws, size_t ws_size,
                              hipStream_t stream)
{
    const float* batch = (const float*)d_in[0];
    const int*   trip  = (const int*)d_in[1];
    float* out = (float*)d_out;
    const int T     = in_sizes[1] / 3;
    const int ND    = in_sizes[0];
    const int nrows = ND / D;

    const size_t fp8_bytes  = align256((size_t)ND);
    const size_t norm_bytes = align256((size_t)nrows * sizeof(float));
    const size_t cp_bytes   = align256((size_t)NCH * T * sizeof(float));
    const size_t need = fp8_bytes + norm_bytes + cp_bytes + 256 * sizeof(float);

    if (nrows <= NROW && ws_size >= need) {
        unsigned char* ws = (unsigned char*)d_ws;
        uint*  batch8     = (uint*)ws;
        float* norms      = (float*)(ws + fp8_bytes);
        float* chunk_part = (float*)(ws + fp8_bytes + norm_bytes);
        float* part2      = (float*)(ws + fp8_bytes + norm_bytes + cp_bytes);

        convert_norm_kernel<<<1024, 256, 0, stream>>>(batch, batch8, norms, nrows);
        stage_dot_kernel<<<NBLK, 512, 0, stream>>>(batch8, trip, chunk_part, T, nrows);
        chunk_reduce_kernel<<<256, 256, 0, stream>>>(chunk_part, trip, norms, part2, T);
        final_mean_kernel<<<1, 256, 0, stream>>>(part2, 256, out, 1.0f / (float)T);
    } else {
        float* partials = (float*)d_ws;  // 8 KB
        triplet_full_kernel<<<2048, 256, 0, stream>>>(batch, trip, partials, T);
        final_mean_kernel<<<1, 256, 0, stream>>>(partials, 2048, out, 1.0f / (float)T);
    }
}